// Round 10
// baseline (68.663 us; speedup 1.0000x reference)
//
#include <hip/hip_runtime.h>
#include <hip/hip_bf16.h>
#include <math.h>

// S4D layer B=8,H=512,L=2048,N=64 via chunked state-space + MFMA.
// R10 = R4 phase structure (proven), with:
//  - native bf16 converts (v_cvt) in split8 instead of manual RNE bit-twiddle
//  - no E-table: M/W fragments via exact cpow7 ladders from 1KB par_s
//  - scan writes S in-place over w (single shared wS pool, no aliasing anywhere)
//  - LDS 36KB, grid (H, B/4), 4 batches/block, __launch_bounds__(256,4)
//    -> 4 blocks/CU resident.

typedef short bf16x8 __attribute__((ext_vector_type(8)));
typedef float f32x4  __attribute__((ext_vector_type(4)));

#define NCHK 32
#define USTR 68   // f32 row stride (2-way bank alias only)
#define MFMA __builtin_amdgcn_mfma_f32_16x16x32_bf16

static __device__ __forceinline__ short f2bf(float x){
    return (short)__bfloat16_as_ushort(__float2bfloat16(x));
}
static __device__ __forceinline__ float bf2f(short h){
    return __uint_as_float(((unsigned)(unsigned short)h) << 16);
}
static __device__ __forceinline__ void split8(const float* f, bf16x8& hi, bf16x8& lo){
    #pragma unroll
    for (int i=0;i<8;++i){
        const short hv = f2bf(f[i]);
        hi[i] = hv;
        lo[i] = f2bf(f[i] - bf2f(hv));
    }
}
static __device__ __forceinline__ void cmul(float& xr, float& xi, float yr, float yi){
    const float t = xr*yr - xi*yi;
    xi = xr*yi + xi*yr;
    xr = t;
}
// exact complex power base^e (0<=e<128) by square-and-multiply
static __device__ __forceinline__ void cpow7(float br, float bi, int e, float& pr_, float& pi_){
    float pr = 1.0f, pi = 0.0f;
    #pragma unroll
    for (int bit=0; bit<7; ++bit){
        if (e & (1<<bit)) cmul(pr, pi, br, bi);
        cmul(br, bi, br, bi);
    }
    pr_ = pr; pi_ = pi;
}

__global__ void __launch_bounds__(256, 4) s4d_r10(
    const float* __restrict__ u_g, const float* __restrict__ A_re,
    const float* __restrict__ A_im, const float* __restrict__ Cg,
    const float* __restrict__ Dp, const float* __restrict__ log_step,
    float* __restrict__ out, int B, int H, int L)
{
    const int h    = blockIdx.x;
    const int g    = blockIdx.y;              // batches 4g .. 4g+3
    const int tid  = threadIdx.x;
    const int wv   = tid >> 6;
    const int lane = tid & 63;
    const int l15  = lane & 15;
    const int oct  = lane >> 4;

    __shared__ __align__(16) float u_s[2][NCHK][USTR];   // f32 u, double-buffered
    __shared__ __align__(16) float wS[2][NCHK][USTR];    // phase-A w, scan rewrites as S[k-1]
    __shared__ __align__(16) float par_s[64][4];         // [n]{rre,rim,cre,cim}
    __shared__ float K_s[64];

    const int b0 = g*4;

    // ---- issue u(b0) load early ----
    const float* up0 = u_g + ((size_t)b0*H + h) * (size_t)L;
    const float4 a0 = *(const float4*)(up0 + tid*8);
    const float4 a1 = *(const float4*)(up0 + tid*8 + 4);

    const float dt = expf(log_step[h]);

    // ---- per-lane (n = lane) params ----
    const float are = fminf(A_re[h*64 + lane], -1e-4f);
    const float aim = A_im[h*64 + lane];
    const float dre = dt * are, dim = dt * aim;
    float sn_, cs_;
    const float er = expf(dre);
    sincosf(dim, &sn_, &cs_);
    const float rre = er * cs_, rim = er * sn_;          // r = exp(dtA)
    const float den = are*are + aim*aim;
    const float ir  = are/den, ii = -aim/den;            // 1/A
    const float c0r = Cg[(h*64+lane)*2 + 0];
    const float c0i = Cg[(h*64+lane)*2 + 1];
    const float e1r = rre - 1.0f, e1i = rim;
    const float ttr = e1r*ir - e1i*ii;
    const float tti = e1r*ii + e1i*ir;
    const float cre = c0r*ttr - c0i*tti;                 // c = Cc*(exp(dtA)-1)/A
    const float cim = c0r*tti + c0i*ttr;

    if (wv == 0){
        float4 p; p.x = rre; p.y = rim; p.z = cre; p.w = cim;
        *(float4*)&par_s[lane][0] = p;
    }

    // ---- commit u(b0) into u_s[0] ----
    {
        const int ch = (tid*8) >> 6, t0 = (tid*8) & 63;
        *(float4*)&u_s[0][ch][t0]   = a0;
        *(float4*)&u_s[0][ch][t0+4] = a1;
    }

    // ---- K[d] = Re sum_n c_n r_n^d (own-lane walk + shuffle reduce) ----
    {
        float qre = rre, qim = rim;                      // -> r^16 by squaring
        #pragma unroll
        for (int i=0;i<4;++i){ const float t2=qre*qre-qim*qim; qim=2.0f*qre*qim; qre=t2; }
        float wre = 1.0f, wim = 0.0f;                    // r^(16*wv)
        for (int i=0;i<wv;++i) cmul(wre, wim, qre, qim);
        float mre = cre*wre - cim*wim;
        float mim = cre*wim + cim*wre;                   // c * r^(16wv)
        #pragma unroll
        for (int jj=0;jj<16;++jj){
            const int p = wv*16 + jj;
            float red = mre;
            #pragma unroll
            for (int off=32; off; off>>=1) red += __shfl_xor(red, off);
            if (lane == 0) K_s[p] = red;
            cmul(mre, mim, rre, rim);
        }
    }
    __syncthreads();   // covers par_s, K_s, u_s[0]

    // ---- rho = r^64 (lane = n, for the scan) ----
    float rhor, rhoi;
    cpow7(rre, rim, 64, rhor, rhoi);

    // ---- W frags: W[n][t] = r_n^(63-t), rows n = wv*16+l15 (exact ladders) ----
    bf16x8 Whre[2], Wlre[2], Whim[2], Wlim[2];
    {
        const int nw = wv*16 + l15;
        const float4 pw = *(const float4*)&par_s[nw][0];
        const float rwr = pw.x, rwi = pw.y;
        #pragma unroll
        for (int kh=0; kh<2; ++kh){
            const int elo = 56 - kh*32 - oct*8;          // 63 - (kh*32+oct*8+7)
            float vr, vi; cpow7(rwr, rwi, elo, vr, vi);
            float fr[8], fi[8];
            fr[7] = vr; fi[7] = vi;
            #pragma unroll
            for (int i=6;i>=0;--i){
                cmul(vr, vi, rwr, rwi);
                fr[i] = vr; fi[i] = vi;
            }
            split8(fr, Whre[kh], Wlre[kh]);
            split8(fi, Whim[kh], Wlim[kh]);
        }
    }
    // ---- M frags: M[j][n] = c_n r_n^(j+1) (re / -im), rows j = wv*16+l15 ----
    bf16x8 Mhre[2], Mlre[2], Mhni[2], Mlni[2];
    {
        const int jp1 = wv*16 + l15 + 1;
        #pragma unroll
        for (int kh=0; kh<2; ++kh){
            float fr[8], fn[8];
            #pragma unroll
            for (int i=0;i<8;++i){
                const int n3 = kh*32 + oct*8 + i;
                const float4 pp = *(const float4*)&par_s[n3][0];
                float pr, pi2; cpow7(pp.x, pp.y, jp1, pr, pi2);
                fr[i] =  pp.z*pr - pp.w*pi2;             // Re(c r^(j+1))
                fn[i] = -(pp.z*pi2 + pp.w*pr);           // -Im(c r^(j+1))
            }
            split8(fr, Mhre[kh], Mlre[kh]);
            split8(fn, Mhni[kh], Mlni[kh]);
        }
    }
    // ---- T frags: T[j][t] = K[j-t], t<j (diagonal excluded) ----
    bf16x8 Th[2], Tl[2];
    #pragma unroll
    for (int kh=0; kh<2; ++kh){
        float ft[8];
        #pragma unroll
        for (int i=0;i<8;++i){
            const int d = (wv*16 + l15) - (kh*32 + oct*8 + i);
            ft[i] = (d > 0) ? K_s[d] : 0.0f;
        }
        split8(ft, Th[kh], Tl[kh]);
    }
    const float DK = Dp[h] + K_s[0];                     // diagonal in f32 epilogue

    // ---- 4 batches ----
    for (int b=0; b<4; ++b){
        const int buf = b & 1;
        const size_t obase = ((size_t)(b0+b)*H + h) * (size_t)L;
        float4 p0 = {0,0,0,0}, p1 = {0,0,0,0};
        const bool pf = (b < 3);
        if (pf){
            const float* up = u_g + ((size_t)(b0+b+1)*H + h) * (size_t)L;
            p0 = *(const float4*)(up + tid*8);
            p1 = *(const float4*)(up + tid*8 + 4);
        }
        // per-wave U hi/lo split from f32 LDS
        bf16x8 Uh[2][2], Ul[2][2];
        #pragma unroll
        for (int ct=0; ct<2; ++ct){
            const int ch = ct*16 + l15;
            #pragma unroll
            for (int kh=0; kh<2; ++kh){
                const float4 x0 = *(const float4*)&u_s[buf][ch][kh*32 + oct*8];
                const float4 x1 = *(const float4*)&u_s[buf][ch][kh*32 + oct*8 + 4];
                const float f[8] = {x0.x,x0.y,x0.z,x0.w,x1.x,x1.y,x1.z,x1.w};
                split8(f, Uh[ct][kh], Ul[ct][kh]);
            }
        }
        // phase A: w[n,k] = sum_t r^(63-t) u[64k+t]  (3-term)
        #pragma unroll
        for (int ct=0; ct<2; ++ct){
            f32x4 ar = {0.f,0.f,0.f,0.f}, ai = {0.f,0.f,0.f,0.f};
            #pragma unroll
            for (int kh=0; kh<2; ++kh){
                ar = MFMA(Whre[kh], Uh[ct][kh], ar, 0,0,0);
                ar = MFMA(Whre[kh], Ul[ct][kh], ar, 0,0,0);
                ar = MFMA(Wlre[kh], Uh[ct][kh], ar, 0,0,0);
                ai = MFMA(Whim[kh], Uh[ct][kh], ai, 0,0,0);
                ai = MFMA(Whim[kh], Ul[ct][kh], ai, 0,0,0);
                ai = MFMA(Wlim[kh], Uh[ct][kh], ai, 0,0,0);
            }
            const int ch = ct*16 + l15;
            const int n0 = wv*16 + oct*4;
            *(f32x4*)&wS[0][ch][n0] = ar;
            *(f32x4*)&wS[1][ch][n0] = ai;
        }
        __syncthreads();
        // phase B: scan (wave 0, lane = n); S[k-1] written in-place over w[k]
        if (wv == 0){
            float sr = 0.0f, si = 0.0f;
            #pragma unroll 4
            for (int k=0;k<NCHK;++k){
                const float wr2 = wS[0][k][lane];
                const float wi2 = wS[1][k][lane];
                wS[0][k][lane] = sr; wS[1][k][lane] = si;    // S[k-1]
                const float t2 = fmaf(rhor, sr, fmaf(-rhoi, si, wr2));
                si = fmaf(rhor, si, fmaf(rhoi, sr, wi2));
                sr = t2;
            }
        }
        __syncthreads();
        // phase C: y = Re(M S[k-1]) + T u (3-term) + (D+K0) u (f32 epilogue)
        #pragma unroll
        for (int ct=0; ct<2; ++ct){
            const int ch = ct*16 + l15;
            bf16x8 Srh[2], Srl[2], Sih[2], Sil[2];
            #pragma unroll
            for (int kh=0; kh<2; ++kh){
                {
                    const float4 x0 = *(const float4*)&wS[0][ch][kh*32+oct*8];
                    const float4 x1 = *(const float4*)&wS[0][ch][kh*32+oct*8+4];
                    const float f[8] = {x0.x,x0.y,x0.z,x0.w,x1.x,x1.y,x1.z,x1.w};
                    split8(f, Srh[kh], Srl[kh]);
                }
                {
                    const float4 x0 = *(const float4*)&wS[1][ch][kh*32+oct*8];
                    const float4 x1 = *(const float4*)&wS[1][ch][kh*32+oct*8+4];
                    const float f[8] = {x0.x,x0.y,x0.z,x0.w,x1.x,x1.y,x1.z,x1.w};
                    split8(f, Sih[kh], Sil[kh]);
                }
            }
            f32x4 acc = {0.f,0.f,0.f,0.f};
            #pragma unroll
            for (int kh=0; kh<2; ++kh){
                acc = MFMA(Mhre[kh], Srh[kh], acc, 0,0,0);
                acc = MFMA(Mhre[kh], Srl[kh], acc, 0,0,0);
                acc = MFMA(Mlre[kh], Srh[kh], acc, 0,0,0);
                acc = MFMA(Mhni[kh], Sih[kh], acc, 0,0,0);
                acc = MFMA(Mhni[kh], Sil[kh], acc, 0,0,0);
                acc = MFMA(Mlni[kh], Sih[kh], acc, 0,0,0);
                acc = MFMA(Th[kh], Uh[ct][kh], acc, 0,0,0);
                acc = MFMA(Th[kh], Ul[ct][kh], acc, 0,0,0);
                acc = MFMA(Tl[kh], Uh[ct][kh], acc, 0,0,0);
            }
            const int j0 = wv*16 + oct*4;
            const float4 uu = *(const float4*)&u_s[buf][ch][j0];
            float4 y;
            y.x = acc[0] + DK*uu.x;
            y.y = acc[1] + DK*uu.y;
            y.z = acc[2] + DK*uu.z;
            y.w = acc[3] + DK*uu.w;
            *(float4*)(out + obase + (size_t)(ch*64 + j0)) = y;
        }
        // commit prefetched u (f32) into the other buffer
        if (pf){
            const int ch2 = (tid*8) >> 6, t0 = (tid*8) & 63;
            *(float4*)&u_s[buf^1][ch2][t0]   = p0;
            *(float4*)&u_s[buf^1][ch2][t0+4] = p1;
        }
        __syncthreads();
    }
}

extern "C" void kernel_launch(void* const* d_in, const int* in_sizes, int n_in,
                              void* d_out, int out_size, void* d_ws, size_t ws_size,
                              hipStream_t stream) {
    const float* u        = (const float*)d_in[0];
    const float* A_re     = (const float*)d_in[1];
    const float* A_im     = (const float*)d_in[2];
    const float* C        = (const float*)d_in[3];
    const float* Dp       = (const float*)d_in[4];
    const float* log_step = (const float*)d_in[5];
    float* out = (float*)d_out;

    const int H = in_sizes[4];                 // 512
    const int L = 2048;                        // fixed by problem
    const int B = in_sizes[0] / (H * L);       // 8
    (void)d_ws; (void)ws_size; (void)out_size; (void)n_in;

    dim3 grid(H, B / 4);
    dim3 block(256);
    hipLaunchKernelGGL(s4d_r10, grid, block, 0, stream,
                       u, A_re, A_im, C, Dp, log_step, out, B, H, L);
}